// Round 4
// baseline (582.949 us; speedup 1.0000x reference)
//
#include <hip/hip_runtime.h>
#include <hip/hip_bf16.h>
#include <stdint.h>

typedef __bf16 bf16;
typedef bf16 bf16x8 __attribute__((ext_vector_type(8)));
typedef bf16 bf16x4 __attribute__((ext_vector_type(4)));
typedef float f32x4 __attribute__((ext_vector_type(4)));

constexpr int N = 2048;   // tokens
constexpr int C = 1024;   // model dim
constexpr int H = 2048;   // hidden dim
constexpr int E = 8;      // experts
constexpr float EPS = 1.1920929e-07f;

constexpr int BM = 64, BN = 64, BK = 32;   // 64x64 tile: 4x block count vs 128x128
constexpr int GT = 32;                     // tokens per gate block

// ---------------------------------------------------------------- small init
__global__ void init_kernel(int* counts, float* scoresums) {
  int t = threadIdx.x;
  if (t < E) counts[t] = 0;
  if (t < E) scoresums[t] = 0.f;
}

// ------------------------------------------------- fp32 -> bf16 cvt (merged)
__global__ void cvt_all_kernel(const float* __restrict__ w1, const float* __restrict__ w2,
                               const float* __restrict__ kw, const float* __restrict__ vw,
                               bf16* __restrict__ w1b, bf16* __restrict__ w2b,
                               bf16* __restrict__ kwb, bf16* __restrict__ vwb) {
  size_t i = (size_t)blockIdx.x * 256 + threadIdx.x;     // float4 units
  const size_t n1 = (size_t)E * H * C / 4;
  const size_t n2 = n1 * 2;
  const size_t n3 = n2 + (size_t)H * C / 4;
  const float4* src; bf16x4* dst; size_t off;
  if (i < n1)      { src = (const float4*)w1; dst = (bf16x4*)w1b; off = i; }
  else if (i < n2) { src = (const float4*)w2; dst = (bf16x4*)w2b; off = i - n1; }
  else if (i < n3) { src = (const float4*)kw; dst = (bf16x4*)kwb; off = i - n2; }
  else             { src = (const float4*)vw; dst = (bf16x4*)vwb; off = i - n3; }
  float4 v = src[off];
  bf16x4 o = { (bf16)v.x, (bf16)v.y, (bf16)v.z, (bf16)v.w };
  dst[off] = o;
}

// --------------------------------------------------------------- rmsnorm(x)
__global__ void rmsnorm_kernel(const float* __restrict__ x,
                               bf16* __restrict__ xtb,
                               float* __restrict__ rs1_arr,
                               float* __restrict__ rs2_arr) {
  int n = blockIdx.x;
  int tid = threadIdx.x;                      // 256 threads, 1 float4 each
  float4 v = ((const float4*)(x + (size_t)n * C))[tid];
  float ss = v.x*v.x + v.y*v.y + v.z*v.z + v.w*v.w;
  #pragma unroll
  for (int off = 32; off > 0; off >>= 1) ss += __shfl_down(ss, off, 64);
  __shared__ float red[4];
  __shared__ float tot;
  int wave = tid >> 6, lane = tid & 63;
  if (lane == 0) red[wave] = ss;
  __syncthreads();
  if (tid == 0) tot = red[0] + red[1] + red[2] + red[3];
  __syncthreads();
  float sumsq = tot;
  float rs1 = rsqrtf(sumsq * (1.f / C) + EPS);
  bf16x4 o = { (bf16)(v.x*rs1), (bf16)(v.y*rs1), (bf16)(v.z*rs1), (bf16)(v.w*rs1) };
  ((bf16x4*)(xtb + (size_t)n * C))[tid] = o;
  if (tid == 0) {
    rs1_arr[n] = rs1;
    float m2 = sumsq * rs1 * rs1 * (1.f / C);  // mean(xt^2) exactly
    rs2_arr[n] = rsqrtf(m2 + EPS);
  }
}

// ------------------------------------------------------------------- gating
// Block-aggregated (R3): LDS atomics within block, 16 global atomics/block.
__global__ __launch_bounds__(256) void gate_kernel(
    const float* __restrict__ x, const float* __restrict__ rs1_arr,
    const float* __restrict__ gate_w, const float* __restrict__ sgw,
    float* __restrict__ g, float* __restrict__ sgbuf,
    int* __restrict__ counts, int* __restrict__ lists,
    float* __restrict__ scoresums) {
  __shared__ float wsm[9][1024];   // 36 KB: 8 expert rows + shared-gate row
  __shared__ float s_scores[8];
  __shared__ int   s_cnt[8];
  __shared__ int   s_base[8];
  __shared__ int   s_e1[GT], s_p1[GT], s_e2[GT], s_p2[GT];
  const int tid = threadIdx.x, lane = tid & 63, wave = tid >> 6;
  for (int i = tid; i < 9 * 1024; i += 256) {
    int e = i >> 10, c = i & 1023;
    wsm[e][c] = (e < 8) ? gate_w[i] : sgw[c];
  }
  if (tid < 8) { s_scores[tid] = 0.f; s_cnt[tid] = 0; }
  __syncthreads();

  const int tok0 = blockIdx.x * GT + wave * (GT / 4);
  for (int tt = 0; tt < GT / 4; ++tt) {
    const int tok = tok0 + tt;
    const float* xr = x + (size_t)tok * C;
    float acc[9];
    #pragma unroll
    for (int e = 0; e < 9; e++) acc[e] = 0.f;
    #pragma unroll
    for (int k = 0; k < 16; ++k) {
      int c = k * 64 + lane;
      float xv = xr[c];
      #pragma unroll
      for (int e = 0; e < 9; e++) acc[e] = fmaf(xv, wsm[e][c], acc[e]);
    }
    #pragma unroll
    for (int e = 0; e < 9; e++) {
      float v = acc[e];
      #pragma unroll
      for (int off = 32; off > 0; off >>= 1) v += __shfl_xor(v, off, 64);
      acc[e] = v;
    }
    if (lane == 0) {
      float rs1 = rs1_arr[tok];
      float raw[9];
      #pragma unroll
      for (int e = 0; e < 9; e++) raw[e] = acc[e] * rs1;
      float m = raw[0];
      for (int e = 1; e < 8; e++) m = fmaxf(m, raw[e]);
      float sc[8], s = 0.f;
      for (int e = 0; e < 8; e++) { sc[e] = expf(raw[e] - m); s += sc[e]; }
      float inv = 1.f / s;
      for (int e = 0; e < 8; e++) sc[e] *= inv;
      int i1 = 0;
      for (int e = 1; e < 8; e++) if (sc[e] > sc[i1]) i1 = e;
      int i2 = -1;
      for (int e = 0; e < 8; e++) {
        if (e == i1) continue;
        if (i2 < 0 || sc[e] > sc[i2]) i2 = e;
      }
      float denom = sc[i1] + sc[i2] + 1e-6f;
      float* gr = g + (size_t)tok * E;
      #pragma unroll
      for (int e = 0; e < 8; e++) gr[e] = 0.f;
      gr[i1] = sc[i1] / denom;
      gr[i2] = sc[i2] / denom;
      sgbuf[tok] = 1.f / (1.f + expf(-raw[8]));
      for (int e = 0; e < 8; e++) atomicAdd(&s_scores[e], sc[e]);  // LDS
      int lt = wave * (GT / 4) + tt;
      int p1 = atomicAdd(&s_cnt[i1], 1);   // LDS
      int p2 = atomicAdd(&s_cnt[i2], 1);   // LDS
      s_e1[lt] = i1; s_p1[lt] = p1;
      s_e2[lt] = i2; s_p2[lt] = p2;
    }
  }
  __syncthreads();
  if (tid < 8) {
    s_base[tid] = atomicAdd(&counts[tid], s_cnt[tid]);   // 8 global atomics
    atomicAdd(&scoresums[tid], s_scores[tid]);           // 8 global atomics
  }
  __syncthreads();
  if (tid < GT) {
    int tok = blockIdx.x * GT + tid;
    int e1 = s_e1[tid], e2 = s_e2[tid];
    lists[e1 * N + s_base[e1] + s_p1[tid]] = (tok << 1);
    lists[e2 * N + s_base[e2] + s_p2[tid]] = (tok << 1) | 1;
  }
}

// -------------------------------------------------------- MFMA GEMM mainloop
// 64x64 tile, BK=32. LDS tiles row-major [64][32] bf16 (64B rows). Each wave
// stages quarter w of As AND Bs (1 KB each, wave-uniform base + lane*16) and
// computes quadrant (mb,nb) = ((w&1)*32, (w>>1)*32) with 2x2 16x16x32 MFMAs.
__device__ __forceinline__ void mfma_loop64(
    const char* gA, const char* gB, char* As, char* Bs,
    int wave, int lane, int kIters, int mb, int nb, f32x4 acc[2][2]) {
  const int q = wave * 1024;                  // staging quarter base
  const int arow = lane & 15;
  const int koff = (lane >> 4) * 16;          // quad*8 elems * 2B
  for (int kt = 0; kt < kIters; ++kt) {
    __builtin_amdgcn_global_load_lds((__attribute__((address_space(1))) void*)gA,
                                     (__attribute__((address_space(3))) void*)(As + q), 16, 0, 0);
    __builtin_amdgcn_global_load_lds((__attribute__((address_space(1))) void*)gB,
                                     (__attribute__((address_space(3))) void*)(Bs + q), 16, 0, 0);
    gA += BK * 2; gB += BK * 2;
    __syncthreads();
    bf16x8 a[2], b[2];
    #pragma unroll
    for (int i = 0; i < 2; ++i) {
      a[i] = *(const bf16x8*)(As + (mb + i * 16 + arow) * 64 + koff);
      b[i] = *(const bf16x8*)(Bs + (nb + i * 16 + arow) * 64 + koff);
    }
    #pragma unroll
    for (int i = 0; i < 2; ++i)
      #pragma unroll
      for (int j = 0; j < 2; ++j)
        acc[i][j] = __builtin_amdgcn_mfma_f32_16x16x32_bf16(a[i], b[j], acc[i][j], 0, 0, 0);
    __syncthreads();
  }
}

#define GEMM_PROLOGUE64                                            \
  const int tid = threadIdx.x;                                     \
  const int lane = tid & 63, wave = tid >> 6;                      \
  const int srow = wave * 16 + (lane >> 2);  /* staging tile row */\
  const int scb = (lane & 3) * 16;           /* staging col byte */\
  const int mb = (wave & 1) * 32, nb = (wave >> 1) * 32;           \
  const int col = lane & 15, quad = lane >> 4;                     \
  __shared__ __align__(16) char As[BM * BK * 2];                   \
  __shared__ __align__(16) char Bs[BN * BK * 2];                   \
  f32x4 acc[2][2] = {};

// -------------------------------------------- expert up-proj (gathered GEMM)
__global__ __launch_bounds__(256) void up_kernel(
    const bf16* __restrict__ xtb, const bf16* __restrict__ w1b,
    const float* __restrict__ g, const int* __restrict__ lists,
    const int* __restrict__ counts, bf16* __restrict__ hb) {
  const int e = blockIdx.y;
  const int cnt = counts[e];
  const int m0 = blockIdx.x * BM;
  if (m0 >= cnt) return;
  const int h0 = blockIdx.z * BN;
  GEMM_PROLOGUE64
  __shared__ int toks[BM];
  if (tid < BM) toks[tid] = lists[e * N + min(m0 + tid, cnt - 1)];
  __syncthreads();
  const char* gA = (const char*)xtb + ((size_t)(toks[srow] >> 1) * C) * 2 + scb;
  const char* gB = (const char*)w1b + ((size_t)e * H * C + (size_t)(h0 + srow) * C) * 2 + scb;
  mfma_loop64(gA, gB, As, Bs, wave, lane, C / BK, mb, nb, acc);
  #pragma unroll
  for (int mi = 0; mi < 2; mi++) {
    #pragma unroll
    for (int r = 0; r < 4; r++) {
      int ml = mb + mi * 16 + quad * 4 + r;
      if (m0 + ml < cnt) {
        int packed = toks[ml];
        float gv = g[(size_t)(packed >> 1) * E + e];
        size_t base = (size_t)packed * H + h0 + nb;
        #pragma unroll
        for (int ni = 0; ni < 2; ni++) {
          float v = fmaxf(acc[mi][ni][r], 0.f);
          hb[base + ni * 16 + col] = (bf16)(v * v * gv);
        }
      }
    }
  }
}

// ------------------------------------------ expert down-proj (gathered GEMM)
__global__ __launch_bounds__(256) void down_kernel(
    const bf16* __restrict__ hb, const bf16* __restrict__ w2b,
    const int* __restrict__ lists, const int* __restrict__ counts,
    float* __restrict__ out) {
  const int e = blockIdx.y;
  const int cnt = counts[e];
  const int m0 = blockIdx.x * BM;
  if (m0 >= cnt) return;
  const int c0 = blockIdx.z * BN;
  GEMM_PROLOGUE64
  __shared__ int toks[BM];
  if (tid < BM) toks[tid] = lists[e * N + min(m0 + tid, cnt - 1)];
  __syncthreads();
  const char* gA = (const char*)hb + ((size_t)toks[srow] * H) * 2 + scb;
  const char* gB = (const char*)w2b + ((size_t)e * C * H + (size_t)(c0 + srow) * H) * 2 + scb;
  mfma_loop64(gA, gB, As, Bs, wave, lane, H / BK, mb, nb, acc);
  #pragma unroll
  for (int mi = 0; mi < 2; mi++) {
    #pragma unroll
    for (int r = 0; r < 4; r++) {
      int ml = mb + mi * 16 + quad * 4 + r;
      if (m0 + ml < cnt) {
        int tok = toks[ml] >> 1;
        float* orow = out + (size_t)tok * C + c0 + nb;
        #pragma unroll
        for (int ni = 0; ni < 2; ni++) atomicAdd(&orow[ni * 16 + col], acc[mi][ni][r]);
      }
    }
  }
}

// --------------------------------------------------- shared expert: k-proj
// kk = bf16( relu(rs2*(xt.k_w^T) + k_b)^2 )
__global__ __launch_bounds__(256) void kproj_kernel(
    const bf16* __restrict__ xtb, const bf16* __restrict__ kwb,
    const float* __restrict__ rs2, const float* __restrict__ k_b,
    bf16* __restrict__ kkb) {
  const int n0 = blockIdx.x * BM;
  const int h0 = blockIdx.y * BN;
  GEMM_PROLOGUE64
  const char* gA = (const char*)xtb + ((size_t)(n0 + srow) * C) * 2 + scb;
  const char* gB = (const char*)kwb + ((size_t)(h0 + srow) * C) * 2 + scb;
  mfma_loop64(gA, gB, As, Bs, wave, lane, C / BK, mb, nb, acc);
  #pragma unroll
  for (int mi = 0; mi < 2; mi++) {
    #pragma unroll
    for (int r = 0; r < 4; r++) {
      int n = n0 + mb + mi * 16 + quad * 4 + r;
      float rs = rs2[n];
      #pragma unroll
      for (int ni = 0; ni < 2; ni++) {
        int h = h0 + nb + ni * 16 + col;
        float v = fmaf(acc[mi][ni][r], rs, k_b[h]);
        v = fmaxf(v, 0.f);
        kkb[(size_t)n * H + h] = (bf16)(v * v);
      }
    }
  }
}

// --------------------------------------------------- shared expert: v-proj
// out += sg*(kk.v_w^T + v_b), split-K2: each slice atomicAdds its partial;
// slice 0 also adds the sg*v_b term. Commutes with down_kernel's atomics.
__global__ __launch_bounds__(256) void vproj_kernel(
    const bf16* __restrict__ kkb, const bf16* __restrict__ vwb,
    const float* __restrict__ v_b, const float* __restrict__ sg,
    float* __restrict__ out) {
  const int n0 = blockIdx.x * BM;
  const int c0 = blockIdx.y * BN;
  const int ks = blockIdx.z;                 // 0 or 1: K-slice of H
  GEMM_PROLOGUE64
  const size_t kofs = (size_t)ks * (H / 2) * 2;   // byte offset into K
  const char* gA = (const char*)kkb + ((size_t)(n0 + srow) * H) * 2 + kofs + scb;
  const char* gB = (const char*)vwb + ((size_t)(c0 + srow) * H) * 2 + kofs + scb;
  mfma_loop64(gA, gB, As, Bs, wave, lane, (H / 2) / BK, mb, nb, acc);
  #pragma unroll
  for (int mi = 0; mi < 2; mi++) {
    #pragma unroll
    for (int r = 0; r < 4; r++) {
      int n = n0 + mb + mi * 16 + quad * 4 + r;
      float sgv = sg[n];
      #pragma unroll
      for (int ni = 0; ni < 2; ni++) {
        int c = c0 + nb + ni * 16 + col;
        float add = sgv * acc[mi][ni][r];
        if (ks == 0) add += sgv * v_b[c];
        atomicAdd(&out[(size_t)n * C + c], add);
      }
    }
  }
}

// -------------------------------------------------------------------- aux
// onehot column-mean is exactly 0.5*counts[e]/N
__global__ void aux_kernel(const float* __restrict__ scoresums,
                           const int* __restrict__ counts,
                           float* __restrict__ out_aux) {
  if (threadIdx.x == 0) {
    float a = 0.f;
    for (int e = 0; e < 8; e++)
      a += (0.5f * (float)counts[e] * (1.f / N)) * (scoresums[e] * (1.f / N));
    out_aux[0] = 8.f * a * 0.01f;
  }
}

extern "C" void kernel_launch(void* const* d_in, const int* in_sizes, int n_in,
                              void* d_out, int out_size, void* d_ws, size_t ws_size,
                              hipStream_t stream) {
  (void)in_sizes; (void)n_in; (void)ws_size;
  const float* x   = (const float*)d_in[0];
  const float* gw  = (const float*)d_in[1];
  const float* w1  = (const float*)d_in[2];
  const float* w2  = (const float*)d_in[3];
  const float* sgw = (const float*)d_in[4];
  const float* k_w = (const float*)d_in[5];
  const float* k_b = (const float*)d_in[6];
  const float* v_w = (const float*)d_in[7];
  const float* v_b = (const float*)d_in[8];
  float* out = (float*)d_out;

  // workspace layout (~97 MiB)
  char* p = (char*)d_ws;
  auto alloc = [&](size_t bytes) { char* r = p; p += (bytes + 255) & ~255ull; return r; };
  bf16* xtb  = (bf16*)alloc((size_t)N * C * 2);
  bf16* w1b  = (bf16*)alloc((size_t)E * H * C * 2);
  bf16* w2b  = (bf16*)alloc((size_t)E * C * H * 2);
  bf16* kwb  = (bf16*)alloc((size_t)H * C * 2);
  bf16* vwb  = (bf16*)alloc((size_t)C * H * 2);
  bf16* hb   = (bf16*)alloc((size_t)2 * N * H * 2);  // [2N][H], packed-slot rows
  bf16* kkb  = hb;  // alias: down reads hb strictly before kproj writes kkb
  float* rs1 = (float*)alloc((size_t)N * 4);
  float* rs2 = (float*)alloc((size_t)N * 4);
  float* g   = (float*)alloc((size_t)N * E * 4);
  float* sg  = (float*)alloc((size_t)N * 4);
  float* scoresums = (float*)alloc(64);
  int* counts = (int*)alloc(64);
  int* lists  = (int*)alloc((size_t)E * N * 4);

  hipMemsetAsync(d_out, 0, (size_t)out_size * sizeof(float), stream);
  init_kernel<<<1, 32, 0, stream>>>(counts, scoresums);
  {
    const size_t total4 = ((size_t)E * H * C * 2 + (size_t)H * C * 2) / 4;  // float4 count
    cvt_all_kernel<<<(int)(total4 / 256), 256, 0, stream>>>(w1, w2, k_w, v_w, w1b, w2b, kwb, vwb);
  }
  rmsnorm_kernel<<<N, 256, 0, stream>>>(x, xtb, rs1, rs2);
  gate_kernel<<<N / GT, 256, 0, stream>>>(x, rs1, gw, sgw, g, sg, counts, lists, scoresums);
  up_kernel<<<dim3(N / BM, E, H / BN), 256, 0, stream>>>(xtb, w1b, g, lists, counts, hb);
  down_kernel<<<dim3(N / BM, E, C / BN), 256, 0, stream>>>(hb, w2b, lists, counts, out);
  kproj_kernel<<<dim3(N / BM, H / BN), 256, 0, stream>>>(xtb, kwb, rs2, k_b, kkb);
  vproj_kernel<<<dim3(N / BM, C / BN, 2), 256, 0, stream>>>(kkb, vwb, v_b, sg, out);
  aux_kernel<<<1, 64, 0, stream>>>(scoresums, counts, out + (size_t)N * C);
}